// Round 22
// baseline (158.386 us; speedup 1.0000x reference)
//
#include <hip/hip_runtime.h>
#include <math.h>

// Problem constants: B=2, T=2048, E=1024, H=16, D=64
#define TT 2048
#define EE 1024
#define HH 16
#define DD 64
#define BB 2

// exp(0.125*x) = exp2(C8*x); exp(0.5*x) = exp2(CH*x)
#define C8 0.18033688011112042f
#define CH 0.7213475204444817f

typedef __bf16 bf16_t;
typedef __attribute__((ext_vector_type(8))) __bf16 bf16x8;
typedef __attribute__((ext_vector_type(4))) float f32x4;

__device__ __forceinline__ unsigned short f2b(float v) {
    return __builtin_bit_cast(unsigned short, (__bf16)v);
}

// async global->LDS, 16B per lane; LDS dest = wave-uniform base + lane*16
__device__ __forceinline__ void gll16(const void* g, void* l) {
    __builtin_amdgcn_global_load_lds(
        (const __attribute__((address_space(1))) void*)g,
        (__attribute__((address_space(3))) void*)l, 16, 0, 0);
}

// ---------------------------------------------------------------------------
// Threefry-2x32, JAX partitionable stream, key=(0,42). Verified round 3.
// ---------------------------------------------------------------------------
__device__ __forceinline__ unsigned int rotl32(unsigned int x, int r) {
    return (x << r) | (x >> (32 - r));
}

__device__ __forceinline__ float gumbel_for(unsigned int f) {
    const unsigned int ks0 = 0u;
    const unsigned int ks1 = 42u;
    const unsigned int ks2 = 0x1BD11BDAu ^ ks0 ^ ks1;

    unsigned int v0 = 0u + ks0;
    unsigned int v1 = f  + ks1;

    v0 += v1; v1 = rotl32(v1, 13); v1 ^= v0;
    v0 += v1; v1 = rotl32(v1, 15); v1 ^= v0;
    v0 += v1; v1 = rotl32(v1, 26); v1 ^= v0;
    v0 += v1; v1 = rotl32(v1,  6); v1 ^= v0;
    v0 += ks1; v1 += ks2 + 1u;
    v0 += v1; v1 = rotl32(v1, 17); v1 ^= v0;
    v0 += v1; v1 = rotl32(v1, 29); v1 ^= v0;
    v0 += v1; v1 = rotl32(v1, 16); v1 ^= v0;
    v0 += v1; v1 = rotl32(v1, 24); v1 ^= v0;
    v0 += ks2; v1 += ks0 + 2u;
    v0 += v1; v1 = rotl32(v1, 13); v1 ^= v0;
    v0 += v1; v1 = rotl32(v1, 15); v1 ^= v0;
    v0 += v1; v1 = rotl32(v1, 26); v1 ^= v0;
    v0 += v1; v1 = rotl32(v1,  6); v1 ^= v0;
    v0 += ks0; v1 += ks1 + 3u;
    v0 += v1; v1 = rotl32(v1, 17); v1 ^= v0;
    v0 += v1; v1 = rotl32(v1, 29); v1 ^= v0;
    v0 += v1; v1 = rotl32(v1, 16); v1 ^= v0;
    v0 += v1; v1 = rotl32(v1, 24); v1 ^= v0;
    v0 += ks1; v1 += ks2 + 4u;
    v0 += v1; v1 = rotl32(v1, 13); v1 ^= v0;
    v0 += v1; v1 = rotl32(v1, 15); v1 ^= v0;
    v0 += v1; v1 = rotl32(v1, 26); v1 ^= v0;
    v0 += v1; v1 = rotl32(v1,  6); v1 ^= v0;
    v0 += ks2; v1 += ks0 + 5u;

    unsigned int bits = v0 ^ v1;
    unsigned int fb = (bits >> 9) | 0x3F800000u;
    float u01 = __uint_as_float(fb) - 1.0f;
    const float mn = 1e-6f;
    const float mx = 1.0f - 1e-6f;
    float u = fmaxf(mn, u01 * (mx - mn) + mn);
    return -__logf(-__logf(u));
}

// ---------------------------------------------------------------------------
// Prep: convert W->bf16 (grid-stride) + ztile zeroing (blocks 0..31)
// + rsum zeroing (block 32). Replaces 3 launches with 1.
// ---------------------------------------------------------------------------
__global__ __launch_bounds__(256) void prep_kernel(
    const float* __restrict__ W, bf16_t* __restrict__ Wbf,
    bf16_t* __restrict__ dwbf, float* __restrict__ rsum_g)
{
    const int tid = threadIdx.x;
    const int total = 2 * EE * EE / 4;
    for (int idx = blockIdx.x * 256 + tid; idx < total;
         idx += gridDim.x * 256) {
        float4 v = ((const float4*)W)[idx];
        ushort4 o;
        o.x = f2b(v.x); o.y = f2b(v.y); o.z = f2b(v.z); o.w = f2b(v.w);
        ((ushort4*)Wbf)[idx] = o;
    }
    if (blockIdx.x < 32) {
        // zero dw tile (it=2R, jt=2R+1) - the only read-but-never-written tiles
        const int R = blockIdx.x & 15;
        const int b = blockIdx.x >> 4;
        const int i0 = 2 * R * 64, j0 = (2 * R + 1) * 64;
        const bf16x8 z = {};
#pragma unroll
        for (int p = 0; p < 2; ++p) {
            const int idx = p * 256 + tid;
            const int row = idx >> 3, cg = idx & 7;
            *(bf16x8*)(dwbf + (size_t)(b * TT + i0 + row) * TT + j0 + cg * 8) = z;
        }
    } else if (blockIdx.x == 32) {
        const f32x4 z = {0.f, 0.f, 0.f, 0.f};
#pragma unroll
        for (int p = 0; p < 4; ++p)
            ((f32x4*)rsum_g)[p * 256 + tid] = z;   // 4096 floats
    }
}

// ---------------------------------------------------------------------------
// Transpose + convert hs: hsT[b][e][t] = hs[b][t][e]; hsbf[b][t][e] = hs.
// ---------------------------------------------------------------------------
__global__ __launch_bounds__(256) void transpose_kernel(
    const float* __restrict__ hs, bf16_t* __restrict__ hsbf,
    bf16_t* __restrict__ hsT)
{
    __shared__ float ts[64][65];
    const int e0 = blockIdx.x * 64;
    const int t0 = blockIdx.y * 64;
    const int b  = blockIdx.z;
    const int tid = threadIdx.x;
#pragma unroll
    for (int it = 0; it < 16; ++it) {
        const int idx = it * 256 + tid;
        const int tr = idx >> 6, te = idx & 63;
        const float v = hs[((size_t)(b * TT + t0 + tr)) * EE + e0 + te];
        ts[tr][te] = v;
        hsbf[((size_t)(b * TT + t0 + tr)) * EE + e0 + te] = (__bf16)v;
    }
    __syncthreads();
#pragma unroll
    for (int it = 0; it < 16; ++it) {
        const int idx = it * 256 + tid;
        const int er = idx >> 6, tc = idx & 63;
        hsT[((size_t)(b * EE + e0 + er)) * TT + t0 + tc] = (__bf16)ts[tc][er];
    }
}

// ---------------------------------------------------------------------------
// Shared 128x128-tile GEMM main loop (m97 structure): C = A[M,K] . B[N,K]^T.
// nt = number of 32-wide K steps (must be even).
// ---------------------------------------------------------------------------
__device__ __forceinline__ void gemm_mainloop(
    const bf16_t* __restrict__ A, const bf16_t* __restrict__ Bm,
    int K, int nt, int row0, int col0, int wave, int lane,
    bf16_t* Al0, bf16_t* Al1, bf16_t* Bl0, bf16_t* Bl1,
    f32x4 (&acc)[4][4])
{
    const int lrow = lane & 15;
    const int kgrp = lane >> 4;
    const int wr = wave >> 1, wc = wave & 1;
    const int lr4 = lane >> 2;        // staging row within 16
    const int sc  = (lane & 3) * 8;   // staging col (elements)

    auto stage = [&](bf16_t* Ald, bf16_t* Bld, int k0) {
#pragma unroll
        for (int c = 0; c < 2; ++c) {
            const int srow = c * 64 + wave * 16;
            gll16(A  + (size_t)(row0 + srow + lr4) * K + k0 + sc, Ald + srow * 32);
            gll16(Bm + (size_t)(col0 + srow + lr4) * K + k0 + sc, Bld + srow * 32);
        }
    };
    auto compute = [&](const bf16_t* Ald, const bf16_t* Bld) {
        bf16x8 af[4], bfr[4];
#pragma unroll
        for (int m = 0; m < 4; ++m)
            af[m] = *(const bf16x8*)(Ald + (wr * 64 + m * 16 + lrow) * 32 + kgrp * 8);
#pragma unroll
        for (int n = 0; n < 4; ++n)
            bfr[n] = *(const bf16x8*)(Bld + (wc * 64 + n * 16 + lrow) * 32 + kgrp * 8);
        __builtin_amdgcn_s_setprio(1);
#pragma unroll
        for (int m = 0; m < 4; ++m)
#pragma unroll
            for (int n = 0; n < 4; ++n)
                acc[m][n] = __builtin_amdgcn_mfma_f32_16x16x32_bf16(
                    af[m], bfr[n], acc[m][n], 0, 0, 0);
        __builtin_amdgcn_s_setprio(0);
    };

    stage(Al0, Bl0, 0);
    __syncthreads();
#pragma unroll 1
    for (int t = 0; t < nt; t += 2) {
        stage(Al1, Bl1, (t + 1) * 32);
        compute(Al0, Bl0);
        __syncthreads();
        if (t + 2 < nt) stage(Al0, Bl0, (t + 2) * 32);
        compute(Al1, Bl1);
        __syncthreads();
    }
}

// ---------------------------------------------------------------------------
// QK projection: C[r,c] = hsbf[r,:].Wbf[c,:] + bias[c]; c<1024 -> Qbf(b,t,e),
// else Kbf(b,h,t,d).
// ---------------------------------------------------------------------------
__global__ __launch_bounds__(256) void qk_gemm_kernel(
    const bf16_t* __restrict__ hsbf, const bf16_t* __restrict__ Wbf,
    const float* __restrict__ bias,
    bf16_t* __restrict__ Qbf, bf16_t* __restrict__ Kbf)
{
    __shared__ alignas(16) bf16_t Al0[128 * 32], Al1[128 * 32];
    __shared__ alignas(16) bf16_t Bl0[128 * 32], Bl1[128 * 32];

    const int wave = threadIdx.x >> 6;
    const int lane = threadIdx.x & 63;
    const int lrow = lane & 15;
    const int kgrp = lane >> 4;
    const int wr = wave >> 1, wc = wave & 1;
    const int row0 = blockIdx.y * 128;
    const int col0 = blockIdx.x * 128;

    f32x4 acc[4][4] = {};
    gemm_mainloop(hsbf, Wbf, EE, EE / 32, row0, col0, wave, lane,
                  Al0, Al1, Bl0, Bl1, acc);

#pragma unroll
    for (int n = 0; n < 4; ++n) {
        const int cc = col0 + wc * 64 + n * 16 + lrow;
        const float bv = bias[cc];
#pragma unroll
        for (int m = 0; m < 4; ++m) {
#pragma unroll
            for (int r = 0; r < 4; ++r) {
                const int rr = row0 + wr * 64 + m * 16 + 4 * kgrp + r;
                const float v = acc[m][n][r] + bv;
                const int b = rr >> 11, t = rr & (TT - 1);
                if (cc < EE) {
                    Qbf[(size_t)rr * EE + cc] = (__bf16)v;
                } else {
                    const int h = (cc - EE) >> 6, d = (cc - EE) & 63;
                    Kbf[(((size_t)(b * HH + h)) * TT + t) * DD + d] = (__bf16)v;
                }
            }
        }
    }
}

// ---------------------------------------------------------------------------
// out[b] = (1/rowsum) * (dw[b] (TxT bf16) @ hs[b]) with hsT (b,e,t) as B^T.
// TRIANGULAR K-bound: dw[i][j]=0 for j >= row0+128 within this row block.
// ---------------------------------------------------------------------------
__global__ __launch_bounds__(256) void out_gemm_kernel(
    const bf16_t* __restrict__ dwbf, const bf16_t* __restrict__ hsT,
    const float* __restrict__ rsum, float* __restrict__ out)
{
    __shared__ alignas(16) bf16_t Al0[128 * 32], Al1[128 * 32];
    __shared__ alignas(16) bf16_t Bl0[128 * 32], Bl1[128 * 32];

    const int wave = threadIdx.x >> 6;
    const int lane = threadIdx.x & 63;
    const int lrow = lane & 15;
    const int kgrp = lane >> 4;
    const int wr = wave >> 1, wc = wave & 1;
    const int b = blockIdx.z;
    const int row0 = blockIdx.y * 128;   // within [0,T)
    const int col0 = blockIdx.x * 128;   // within [0,E)

    const bf16_t* A  = dwbf + (size_t)b * TT * TT;
    const bf16_t* Bm = hsT  + (size_t)b * EE * TT;

    f32x4 acc[4][4] = {};
    const int klim = row0 + 128;         // multiple of 128 -> nt even
    gemm_mainloop(A, Bm, TT, klim / 32, row0, col0, wave, lane,
                  Al0, Al1, Bl0, Bl1, acc);

    float ri[4][4];
#pragma unroll
    for (int m = 0; m < 4; ++m)
#pragma unroll
        for (int r = 0; r < 4; ++r) {
            const int rr = row0 + wr * 64 + m * 16 + 4 * kgrp + r;
            const float s = rsum[b * TT + rr];
            ri[m][r] = (rr > 0 && s > 0.f) ? 1.0f / s : 0.f;
        }

#pragma unroll
    for (int n = 0; n < 4; ++n) {
        const int cc = col0 + wc * 64 + n * 16 + lrow;
#pragma unroll
        for (int m = 0; m < 4; ++m) {
#pragma unroll
            for (int r = 0; r < 4; ++r) {
                const int rr = row0 + wr * 64 + m * 16 + 4 * kgrp + r;
                out[(size_t)(b * TT + rr) * EE + cc] = acc[m][n][r] * ri[m][r];
            }
        }
    }
}

// ---------------------------------------------------------------------------
// Pass 1: invl[b,h,i] = 1/(H * sum_{j<i} exp(0.125*q_i.k_j)), 0 if empty.
// exp(0.125*s) computed as exp2(C8*s).
// ---------------------------------------------------------------------------
__global__ __launch_bounds__(256) void rowsum_kernel(
    const bf16_t* __restrict__ Qbf, const bf16_t* __restrict__ Kbf,
    float* __restrict__ invl_g)
{
    __shared__ float rsp[4][64];
    const int tid = threadIdx.x;
    const int wave = tid >> 6;
    const int lane = tid & 63;
    const int lrow = lane & 15;
    const int kgrp = lane >> 4;
    const int h = blockIdx.y, b = blockIdx.z;
    const bf16_t* Kh = Kbf + (size_t)(b * HH + h) * TT * DD;

#pragma unroll 1
    for (int pick = 0; pick < 2; ++pick) {
        const int it = pick ? (31 - blockIdx.x) : blockIdx.x;
        const int i0 = it * 64;

        bf16x8 af[4][2];
        const bf16_t* qb = Qbf + (size_t)(b * TT + i0 + lrow) * EE + h * DD;
#pragma unroll
        for (int m = 0; m < 4; ++m) {
            af[m][0] = *(const bf16x8*)(qb + (size_t)(m * 16) * EE + kgrp * 8);
            af[m][1] = *(const bf16x8*)(qb + (size_t)(m * 16) * EE + 32 + kgrp * 8);
        }

        f32x4 rs[4] = {};
#pragma unroll 2
        for (int jt = wave; jt <= it; jt += 4) {
            const int j0 = jt * 64;
            const bf16_t* kb = Kh + (size_t)(j0 + lrow) * DD;
            bf16x8 bk[4][2];
#pragma unroll
            for (int n = 0; n < 4; ++n) {
                bk[n][0] = *(const bf16x8*)(kb + (size_t)(n * 16) * DD + kgrp * 8);
                bk[n][1] = *(const bf16x8*)(kb + (size_t)(n * 16) * DD + 32 + kgrp * 8);
            }
#pragma unroll
            for (int m = 0; m < 4; ++m) {
                f32x4 s[4];
                __builtin_amdgcn_s_setprio(1);
#pragma unroll
                for (int n = 0; n < 4; ++n) {
                    s[n] = f32x4{0.f, 0.f, 0.f, 0.f};
                    s[n] = __builtin_amdgcn_mfma_f32_16x16x32_bf16(af[m][0], bk[n][0], s[n], 0, 0, 0);
                    s[n] = __builtin_amdgcn_mfma_f32_16x16x32_bf16(af[m][1], bk[n][1], s[n], 0, 0, 0);
                }
                __builtin_amdgcn_s_setprio(0);
                if (jt == it) {
#pragma unroll
                    for (int n = 0; n < 4; ++n)
#pragma unroll
                        for (int r = 0; r < 4; ++r) {
                            const int jj = j0 + n * 16 + lrow;
                            const int ii = i0 + m * 16 + 4 * kgrp + r;
                            if (jj < ii) rs[m][r] += exp2f(C8 * s[n][r]);
                        }
                } else {
#pragma unroll
                    for (int n = 0; n < 4; ++n)
#pragma unroll
                        for (int r = 0; r < 4; ++r)
                            rs[m][r] += exp2f(C8 * s[n][r]);
                }
            }
        }
#pragma unroll
        for (int off = 1; off < 16; off <<= 1)
#pragma unroll
            for (int m = 0; m < 4; ++m)
#pragma unroll
                for (int r = 0; r < 4; ++r)
                    rs[m][r] += __shfl_xor(rs[m][r], off);
        if (lrow == 0) {
#pragma unroll
            for (int m = 0; m < 4; ++m)
#pragma unroll
                for (int r = 0; r < 4; ++r)
                    rsp[wave][m * 16 + 4 * kgrp + r] = rs[m][r];
        }
        __syncthreads();
        if (tid < 64) {
            const float tot = rsp[0][tid] + rsp[1][tid] + rsp[2][tid] + rsp[3][tid];
            invl_g[(size_t)(b * HH + h) * TT + i0 + tid] =
                (tot > 0.f) ? 1.0f / (tot * (float)HH) : 0.f;
        }
        __syncthreads();
    }
}

// ---------------------------------------------------------------------------
// Pass 2: round-17/19 structure (25.6 KB LDS, K staged via global_load_lds,
// two-barrier phases, register prefetch of Q/ri one phase ahead,
// deterministic vmcnt(5) ledger). exp via exp2 constant folding.
// ---------------------------------------------------------------------------
__global__ __launch_bounds__(256) void dw_tile_kernel(
    const bf16_t* __restrict__ Qbf, const bf16_t* __restrict__ Kbf,
    const float* __restrict__ invl_g, bf16_t* __restrict__ dwbf,
    float* __restrict__ rsum_g)
{
    __shared__ alignas(16) bf16_t kbuf[2][64 * 64];   // 2 x 8 KB K tile
    __shared__ alignas(16) bf16_t stile[64][72];      // 9 KB out staging

    const int wave = threadIdx.x >> 6;   // = m (row quad)
    const int lane = threadIdx.x & 63;
    const int lrow = lane & 15;
    const int kgrp = lane >> 4;
    const int tid = threadIdx.x;
    const int b = blockIdx.y;

    // XCD swizzle: contiguous chunk of 66 tiles per XCD
    const int tidx = (blockIdx.x & 7) * 66 + (blockIdx.x >> 3);

    int it = (int)((sqrtf(8.0f * tidx + 1.0f) - 1.0f) * 0.5f);
    while ((it + 1) * (it + 2) / 2 <= tidx) ++it;
    while (it * (it + 1) / 2 > tidx) --it;
    const int jt = tidx - it * (it + 1) / 2;
    const bool diag = (it == jt);
    const int i0 = it * 64, j0 = jt * 64;
    const int m = wave;
    const int rbase = i0 + m * 16;            // my 16 rows
    const int nlim = diag ? (m + 1) : 4;

    // staging geometry: wave w covers rows 16w..16w+15 (2 KB = 2 issues)
    int prow[2], pchunk[2];
#pragma unroll
    for (int c = 0; c < 2; ++c) {
        const int p = wave * 2048 + c * 1024 + lane * 16;  // linear byte pos
        prow[c] = p >> 7;                                  // tile row
        pchunk[c] = ((p >> 4) & 7) ^ (prow[c] & 7);        // swizzled 16B chunk
    }
    const bf16_t* Kb0 = Kbf + ((size_t)b * HH * TT + j0) * DD;

    auto stage = [&](int h, int buf) {
#pragma unroll
        for (int c = 0; c < 2; ++c) {
            gll16(Kb0 + (size_t)h * TT * DD + prow[c] * DD + pchunk[c] * 8,
                  (bf16_t*)kbuf[buf] + wave * 1024 + c * 512);
        }
    };

    const bf16_t* qbase = Qbf + (size_t)(b * TT + rbase + lrow) * EE;
    const float*  ribase = invl_g + (size_t)b * HH * TT + rbase + 4 * kgrp;
    const int swz0 = (kgrp ^ (lrow & 7)) * 8;        // chunk 0-3 swizzled
    const int swz1 = ((4 + kgrp) ^ (lrow & 7)) * 8;  // chunk 4-7 swizzled

    f32x4 avg[4] = {};

    // prologue: Q0/ri0 register loads + stage0 (5 vmem ops outstanding)
    bf16x8 a0c = *(const bf16x8*)(qbase + kgrp * 8);
    bf16x8 a1c = *(const bf16x8*)(qbase + 32 + kgrp * 8);
    f32x4  ric = *(const f32x4*)(ribase);
    stage(0, 0);

#pragma unroll 1
    for (int h = 0; h < HH; ++h) {
        const int cur = h & 1;
        bf16x8 a0n, a1n;
        f32x4 rin;
        if (h + 1 < HH) {
            const bf16_t* qb = qbase + (h + 1) * DD;
            a0n = *(const bf16x8*)(qb + kgrp * 8);
            a1n = *(const bf16x8*)(qb + 32 + kgrp * 8);
            rin = *(const f32x4*)(ribase + (size_t)(h + 1) * TT);
            stage(h + 1, cur ^ 1);
            asm volatile("s_waitcnt vmcnt(5)" ::: "memory");
        } else {
            asm volatile("s_waitcnt vmcnt(0)" ::: "memory");
        }
        __builtin_amdgcn_s_barrier();      // kbuf[cur] fully visible

        const bf16_t* kb = kbuf[cur];
        f32x4 s[4];
        __builtin_amdgcn_s_setprio(1);
#pragma unroll
        for (int n = 0; n < 4; ++n) {
            if (n < nlim) {
                const int row = n * 16 + lrow;
                const bf16x8 b0 = *(const bf16x8*)(kb + row * 64 + swz0);
                const bf16x8 b1 = *(const bf16x8*)(kb + row * 64 + swz1);
                s[n] = f32x4{0.f, 0.f, 0.f, 0.f};
                s[n] = __builtin_amdgcn_mfma_f32_16x16x32_bf16(a0c, b0, s[n], 0, 0, 0);
                s[n] = __builtin_amdgcn_mfma_f32_16x16x32_bf16(a1c, b1, s[n], 0, 0, 0);
            }
        }
        __builtin_amdgcn_s_setprio(0);
#pragma unroll
        for (int n = 0; n < 4; ++n) {
            if (n < nlim) {
#pragma unroll
                for (int r = 0; r < 4; ++r)
                    avg[n][r] += exp2f(C8 * s[n][r]) * ric[r];
            }
        }
        __builtin_amdgcn_s_barrier();      // reads of kbuf[cur] done before overwrite
        if (h + 1 < HH) { a0c = a0n; a1c = a1n; ric = rin; }
    }

    // epilogue -> LDS (zeros for masked cells), per-cell gumbel + row sums
    float sr[4] = {0.f, 0.f, 0.f, 0.f};
#pragma unroll
    for (int n = 0; n < 4; ++n) {
        const int jj = j0 + n * 16 + lrow;
#pragma unroll
        for (int r = 0; r < 4; ++r) {
            const int rloc = m * 16 + 4 * kgrp + r;
            const int ii = i0 + rloc;
            float val = 0.f;
            if (n < nlim && jj < ii) {
                const float lg = fminf(fmaxf(avg[n][r], -40.0f), 40.0f);
                const float g = gumbel_for((unsigned)(b * TT + ii) * TT + (unsigned)jj);
                val = exp2f(CH * (lg + g));
            }
            sr[r] += val;
            stile[rloc][n * 16 + lrow] = (__bf16)val;
        }
    }
    // reduce tile-row sums across the 16 j-lanes, one atomicAdd per row
#pragma unroll
    for (int off = 1; off < 16; off <<= 1)
#pragma unroll
        for (int r = 0; r < 4; ++r) sr[r] += __shfl_xor(sr[r], off);
    if (lrow == 0) {
#pragma unroll
        for (int r = 0; r < 4; ++r)
            atomicAdd(&rsum_g[b * TT + rbase + 4 * kgrp + r], sr[r]);
    }
    __syncthreads();

    // coalesced copy-out: 8 lanes cover one 128B row segment
#pragma unroll
    for (int p = 0; p < 2; ++p) {
        const int idx = p * 256 + tid;
        const int row = idx >> 3, cg = idx & 7;
        *(bf16x8*)(dwbf + (size_t)(b * TT + i0 + row) * TT + j0 + cg * 8) =
            *(const bf16x8*)(&stile[row][cg * 8]);
    }
}

// ---------------------------------------------------------------------------
extern "C" void kernel_launch(void* const* d_in, const int* in_sizes, int n_in,
                              void* d_out, int out_size, void* d_ws, size_t ws_size,
                              hipStream_t stream) {
    const float* hs   = (const float*)d_in[0];   // (B,T,E) f32
    const float* W    = (const float*)d_in[1];   // (3E,E)  f32
    const float* bias = (const float*)d_in[2];   // (3E,)   f32
    float* out = (float*)d_out;                  // (B,T,E) f32

    char* ws = (char*)d_ws;
    bf16_t* dwbf   = (bf16_t*)ws;                                  // 16 MB (b,i,j)
    bf16_t* Qbf    = (bf16_t*)(ws + (size_t)16 * 1024 * 1024);     //  8 MB (b,t,e)
    bf16_t* Kbf    = (bf16_t*)(ws + (size_t)24 * 1024 * 1024);     //  8 MB (b,h,t,d)
    bf16_t* hsbf   = (bf16_t*)(ws + (size_t)32 * 1024 * 1024);     //  8 MB
    bf16_t* Wbf    = (bf16_t*)(ws + (size_t)40 * 1024 * 1024);     //  4 MB
    bf16_t* hsT    = (bf16_t*)(ws + (size_t)44 * 1024 * 1024);     //  8 MB (b,e,t)
    float*  invl_g = (float*) (ws + (size_t)52 * 1024 * 1024);     // 256 KB
    float*  rsum_g = (float*) (ws + (size_t)52 * 1024 * 1024 + 256 * 1024); // 16 KB

    prep_kernel<<<512, 256, 0, stream>>>(W, Wbf, dwbf, rsum_g);
    transpose_kernel<<<dim3(EE / 64, TT / 64, BB), 256, 0, stream>>>(hs, hsbf, hsT);
    qk_gemm_kernel<<<dim3(2048 / 128, 4096 / 128), 256, 0, stream>>>(hsbf, Wbf, bias, Qbf, Kbf);
    rowsum_kernel<<<dim3(16, HH, BB), 256, 0, stream>>>(Qbf, Kbf, invl_g);
    dw_tile_kernel<<<dim3(528, BB), 256, 0, stream>>>(Qbf, Kbf, invl_g, dwbf, rsum_g);
    out_gemm_kernel<<<dim3(EE / 128, TT / 128, BB), 256, 0, stream>>>(dwbf, hsT, rsum_g, out);
}

// Round 23
// 140.238 us; speedup vs baseline: 1.1294x; 1.1294x over previous
//
#include <hip/hip_runtime.h>
#include <math.h>

// Problem constants: B=2, T=2048, E=1024, H=16, D=64
#define TT 2048
#define EE 1024
#define HH 16
#define DD 64
#define BB 2

typedef __bf16 bf16_t;
typedef __attribute__((ext_vector_type(8))) __bf16 bf16x8;
typedef __attribute__((ext_vector_type(4))) float f32x4;

__device__ __forceinline__ unsigned short f2b(float v) {
    return __builtin_bit_cast(unsigned short, (__bf16)v);
}

// async global->LDS, 16B per lane; LDS dest = wave-uniform base + lane*16
__device__ __forceinline__ void gll16(const void* g, void* l) {
    __builtin_amdgcn_global_load_lds(
        (const __attribute__((address_space(1))) void*)g,
        (__attribute__((address_space(3))) void*)l, 16, 0, 0);
}

// ---------------------------------------------------------------------------
// Threefry-2x32, JAX partitionable stream, key=(0,42). Verified round 3.
// ---------------------------------------------------------------------------
__device__ __forceinline__ unsigned int rotl32(unsigned int x, int r) {
    return (x << r) | (x >> (32 - r));
}

__device__ __forceinline__ float gumbel_for(unsigned int f) {
    const unsigned int ks0 = 0u;
    const unsigned int ks1 = 42u;
    const unsigned int ks2 = 0x1BD11BDAu ^ ks0 ^ ks1;

    unsigned int v0 = 0u + ks0;
    unsigned int v1 = f  + ks1;

    v0 += v1; v1 = rotl32(v1, 13); v1 ^= v0;
    v0 += v1; v1 = rotl32(v1, 15); v1 ^= v0;
    v0 += v1; v1 = rotl32(v1, 26); v1 ^= v0;
    v0 += v1; v1 = rotl32(v1,  6); v1 ^= v0;
    v0 += ks1; v1 += ks2 + 1u;
    v0 += v1; v1 = rotl32(v1, 17); v1 ^= v0;
    v0 += v1; v1 = rotl32(v1, 29); v1 ^= v0;
    v0 += v1; v1 = rotl32(v1, 16); v1 ^= v0;
    v0 += v1; v1 = rotl32(v1, 24); v1 ^= v0;
    v0 += ks2; v1 += ks0 + 2u;
    v0 += v1; v1 = rotl32(v1, 13); v1 ^= v0;
    v0 += v1; v1 = rotl32(v1, 15); v1 ^= v0;
    v0 += v1; v1 = rotl32(v1, 26); v1 ^= v0;
    v0 += v1; v1 = rotl32(v1,  6); v1 ^= v0;
    v0 += ks0; v1 += ks1 + 3u;
    v0 += v1; v1 = rotl32(v1, 17); v1 ^= v0;
    v0 += v1; v1 = rotl32(v1, 29); v1 ^= v0;
    v0 += v1; v1 = rotl32(v1, 16); v1 ^= v0;
    v0 += v1; v1 = rotl32(v1, 24); v1 ^= v0;
    v0 += ks1; v1 += ks2 + 4u;
    v0 += v1; v1 = rotl32(v1, 13); v1 ^= v0;
    v0 += v1; v1 = rotl32(v1, 15); v1 ^= v0;
    v0 += v1; v1 = rotl32(v1, 26); v1 ^= v0;
    v0 += v1; v1 = rotl32(v1,  6); v1 ^= v0;
    v0 += ks2; v1 += ks0 + 5u;

    unsigned int bits = v0 ^ v1;
    unsigned int fb = (bits >> 9) | 0x3F800000u;
    float u01 = __uint_as_float(fb) - 1.0f;
    const float mn = 1e-6f;
    const float mx = 1.0f - 1e-6f;
    float u = fmaxf(mn, u01 * (mx - mn) + mn);
    return -__logf(-__logf(u));
}

// ---------------------------------------------------------------------------
// Prep: convert W->bf16 (grid-stride) + ztile zeroing (blocks 0..31)
// + rsum zeroing (block 32). Replaces 3 launches with 1.
// ---------------------------------------------------------------------------
__global__ __launch_bounds__(256) void prep_kernel(
    const float* __restrict__ W, bf16_t* __restrict__ Wbf,
    bf16_t* __restrict__ dwbf, float* __restrict__ rsum_g)
{
    const int tid = threadIdx.x;
    const int total = 2 * EE * EE / 4;
    for (int idx = blockIdx.x * 256 + tid; idx < total;
         idx += gridDim.x * 256) {
        float4 v = ((const float4*)W)[idx];
        ushort4 o;
        o.x = f2b(v.x); o.y = f2b(v.y); o.z = f2b(v.z); o.w = f2b(v.w);
        ((ushort4*)Wbf)[idx] = o;
    }
    if (blockIdx.x < 32) {
        // zero dw tile (it=2R, jt=2R+1) - the only read-but-never-written tiles
        const int R = blockIdx.x & 15;
        const int b = blockIdx.x >> 4;
        const int i0 = 2 * R * 64, j0 = (2 * R + 1) * 64;
        const bf16x8 z = {};
#pragma unroll
        for (int p = 0; p < 2; ++p) {
            const int idx = p * 256 + tid;
            const int row = idx >> 3, cg = idx & 7;
            *(bf16x8*)(dwbf + (size_t)(b * TT + i0 + row) * TT + j0 + cg * 8) = z;
        }
    } else if (blockIdx.x == 32) {
        const f32x4 z = {0.f, 0.f, 0.f, 0.f};
#pragma unroll
        for (int p = 0; p < 4; ++p)
            ((f32x4*)rsum_g)[p * 256 + tid] = z;   // 4096 floats
    }
}

// ---------------------------------------------------------------------------
// Transpose + convert hs: hsT[b][e][t] = hs[b][t][e]; hsbf[b][t][e] = hs.
// ---------------------------------------------------------------------------
__global__ __launch_bounds__(256) void transpose_kernel(
    const float* __restrict__ hs, bf16_t* __restrict__ hsbf,
    bf16_t* __restrict__ hsT)
{
    __shared__ float ts[64][65];
    const int e0 = blockIdx.x * 64;
    const int t0 = blockIdx.y * 64;
    const int b  = blockIdx.z;
    const int tid = threadIdx.x;
#pragma unroll
    for (int it = 0; it < 16; ++it) {
        const int idx = it * 256 + tid;
        const int tr = idx >> 6, te = idx & 63;
        const float v = hs[((size_t)(b * TT + t0 + tr)) * EE + e0 + te];
        ts[tr][te] = v;
        hsbf[((size_t)(b * TT + t0 + tr)) * EE + e0 + te] = (__bf16)v;
    }
    __syncthreads();
#pragma unroll
    for (int it = 0; it < 16; ++it) {
        const int idx = it * 256 + tid;
        const int er = idx >> 6, tc = idx & 63;
        hsT[((size_t)(b * EE + e0 + er)) * TT + t0 + tc] = (__bf16)ts[tc][er];
    }
}

// ---------------------------------------------------------------------------
// Shared 128x128-tile GEMM main loop (m97 structure): C = A[M,K] . B[N,K]^T.
// nt = number of 32-wide K steps (must be even).
// ---------------------------------------------------------------------------
__device__ __forceinline__ void gemm_mainloop(
    const bf16_t* __restrict__ A, const bf16_t* __restrict__ Bm,
    int K, int nt, int row0, int col0, int wave, int lane,
    bf16_t* Al0, bf16_t* Al1, bf16_t* Bl0, bf16_t* Bl1,
    f32x4 (&acc)[4][4])
{
    const int lrow = lane & 15;
    const int kgrp = lane >> 4;
    const int wr = wave >> 1, wc = wave & 1;
    const int lr4 = lane >> 2;        // staging row within 16
    const int sc  = (lane & 3) * 8;   // staging col (elements)

    auto stage = [&](bf16_t* Ald, bf16_t* Bld, int k0) {
#pragma unroll
        for (int c = 0; c < 2; ++c) {
            const int srow = c * 64 + wave * 16;
            gll16(A  + (size_t)(row0 + srow + lr4) * K + k0 + sc, Ald + srow * 32);
            gll16(Bm + (size_t)(col0 + srow + lr4) * K + k0 + sc, Bld + srow * 32);
        }
    };
    auto compute = [&](const bf16_t* Ald, const bf16_t* Bld) {
        bf16x8 af[4], bfr[4];
#pragma unroll
        for (int m = 0; m < 4; ++m)
            af[m] = *(const bf16x8*)(Ald + (wr * 64 + m * 16 + lrow) * 32 + kgrp * 8);
#pragma unroll
        for (int n = 0; n < 4; ++n)
            bfr[n] = *(const bf16x8*)(Bld + (wc * 64 + n * 16 + lrow) * 32 + kgrp * 8);
        __builtin_amdgcn_s_setprio(1);
#pragma unroll
        for (int m = 0; m < 4; ++m)
#pragma unroll
            for (int n = 0; n < 4; ++n)
                acc[m][n] = __builtin_amdgcn_mfma_f32_16x16x32_bf16(
                    af[m], bfr[n], acc[m][n], 0, 0, 0);
        __builtin_amdgcn_s_setprio(0);
    };

    stage(Al0, Bl0, 0);
    __syncthreads();
#pragma unroll 1
    for (int t = 0; t < nt; t += 2) {
        stage(Al1, Bl1, (t + 1) * 32);
        compute(Al0, Bl0);
        __syncthreads();
        if (t + 2 < nt) stage(Al0, Bl0, (t + 2) * 32);
        compute(Al1, Bl1);
        __syncthreads();
    }
}

// ---------------------------------------------------------------------------
// QK projection: C[r,c] = hsbf[r,:].Wbf[c,:] + bias[c]; c<1024 -> Qbf(b,t,e),
// else Kbf(b,h,t,d).
// ---------------------------------------------------------------------------
__global__ __launch_bounds__(256) void qk_gemm_kernel(
    const bf16_t* __restrict__ hsbf, const bf16_t* __restrict__ Wbf,
    const float* __restrict__ bias,
    bf16_t* __restrict__ Qbf, bf16_t* __restrict__ Kbf)
{
    __shared__ alignas(16) bf16_t Al0[128 * 32], Al1[128 * 32];
    __shared__ alignas(16) bf16_t Bl0[128 * 32], Bl1[128 * 32];

    const int wave = threadIdx.x >> 6;
    const int lane = threadIdx.x & 63;
    const int lrow = lane & 15;
    const int kgrp = lane >> 4;
    const int wr = wave >> 1, wc = wave & 1;
    const int row0 = blockIdx.y * 128;
    const int col0 = blockIdx.x * 128;

    f32x4 acc[4][4] = {};
    gemm_mainloop(hsbf, Wbf, EE, EE / 32, row0, col0, wave, lane,
                  Al0, Al1, Bl0, Bl1, acc);

#pragma unroll
    for (int n = 0; n < 4; ++n) {
        const int cc = col0 + wc * 64 + n * 16 + lrow;
        const float bv = bias[cc];
#pragma unroll
        for (int m = 0; m < 4; ++m) {
#pragma unroll
            for (int r = 0; r < 4; ++r) {
                const int rr = row0 + wr * 64 + m * 16 + 4 * kgrp + r;
                const float v = acc[m][n][r] + bv;
                const int b = rr >> 11, t = rr & (TT - 1);
                if (cc < EE) {
                    Qbf[(size_t)rr * EE + cc] = (__bf16)v;
                } else {
                    const int h = (cc - EE) >> 6, d = (cc - EE) & 63;
                    Kbf[(((size_t)(b * HH + h)) * TT + t) * DD + d] = (__bf16)v;
                }
            }
        }
    }
}

// ---------------------------------------------------------------------------
// out[b] = (1/rowsum) * (dw[b] (TxT bf16) @ hs[b]) with hsT (b,e,t) as B^T.
// TRIANGULAR K-bound: dw[i][j]=0 for j >= row0+128 within this row block.
// ---------------------------------------------------------------------------
__global__ __launch_bounds__(256) void out_gemm_kernel(
    const bf16_t* __restrict__ dwbf, const bf16_t* __restrict__ hsT,
    const float* __restrict__ rsum, float* __restrict__ out)
{
    __shared__ alignas(16) bf16_t Al0[128 * 32], Al1[128 * 32];
    __shared__ alignas(16) bf16_t Bl0[128 * 32], Bl1[128 * 32];

    const int wave = threadIdx.x >> 6;
    const int lane = threadIdx.x & 63;
    const int lrow = lane & 15;
    const int kgrp = lane >> 4;
    const int wr = wave >> 1, wc = wave & 1;
    const int b = blockIdx.z;
    const int row0 = blockIdx.y * 128;   // within [0,T)
    const int col0 = blockIdx.x * 128;   // within [0,E)

    const bf16_t* A  = dwbf + (size_t)b * TT * TT;
    const bf16_t* Bm = hsT  + (size_t)b * EE * TT;

    f32x4 acc[4][4] = {};
    const int klim = row0 + 128;         // multiple of 128 -> nt even
    gemm_mainloop(A, Bm, TT, klim / 32, row0, col0, wave, lane,
                  Al0, Al1, Bl0, Bl1, acc);

    float ri[4][4];
#pragma unroll
    for (int m = 0; m < 4; ++m)
#pragma unroll
        for (int r = 0; r < 4; ++r) {
            const int rr = row0 + wr * 64 + m * 16 + 4 * kgrp + r;
            const float s = rsum[b * TT + rr];
            ri[m][r] = (rr > 0 && s > 0.f) ? 1.0f / s : 0.f;
        }

#pragma unroll
    for (int n = 0; n < 4; ++n) {
        const int cc = col0 + wc * 64 + n * 16 + lrow;
#pragma unroll
        for (int m = 0; m < 4; ++m) {
#pragma unroll
            for (int r = 0; r < 4; ++r) {
                const int rr = row0 + wr * 64 + m * 16 + 4 * kgrp + r;
                out[(size_t)(b * TT + rr) * EE + cc] = acc[m][n][r] * ri[m][r];
            }
        }
    }
}

// ---------------------------------------------------------------------------
// Pass 1: invl[b,h,i] = 1/(H * sum_{j<i} exp(0.125*q_i.k_j)), 0 if empty.
// jt-loop unroll 2: two independent K-load->MFMA->exp chains in flight.
// ---------------------------------------------------------------------------
__global__ __launch_bounds__(256) void rowsum_kernel(
    const bf16_t* __restrict__ Qbf, const bf16_t* __restrict__ Kbf,
    float* __restrict__ invl_g)
{
    __shared__ float rsp[4][64];
    const int tid = threadIdx.x;
    const int wave = tid >> 6;
    const int lane = tid & 63;
    const int lrow = lane & 15;
    const int kgrp = lane >> 4;
    const int h = blockIdx.y, b = blockIdx.z;
    const bf16_t* Kh = Kbf + (size_t)(b * HH + h) * TT * DD;

#pragma unroll 1
    for (int pick = 0; pick < 2; ++pick) {
        const int it = pick ? (31 - blockIdx.x) : blockIdx.x;
        const int i0 = it * 64;

        bf16x8 af[4][2];
        const bf16_t* qb = Qbf + (size_t)(b * TT + i0 + lrow) * EE + h * DD;
#pragma unroll
        for (int m = 0; m < 4; ++m) {
            af[m][0] = *(const bf16x8*)(qb + (size_t)(m * 16) * EE + kgrp * 8);
            af[m][1] = *(const bf16x8*)(qb + (size_t)(m * 16) * EE + 32 + kgrp * 8);
        }

        f32x4 rs[4] = {};
#pragma unroll 2
        for (int jt = wave; jt <= it; jt += 4) {
            const int j0 = jt * 64;
            const bf16_t* kb = Kh + (size_t)(j0 + lrow) * DD;
            bf16x8 bk[4][2];
#pragma unroll
            for (int n = 0; n < 4; ++n) {
                bk[n][0] = *(const bf16x8*)(kb + (size_t)(n * 16) * DD + kgrp * 8);
                bk[n][1] = *(const bf16x8*)(kb + (size_t)(n * 16) * DD + 32 + kgrp * 8);
            }
#pragma unroll
            for (int m = 0; m < 4; ++m) {
                f32x4 s[4];
                __builtin_amdgcn_s_setprio(1);
#pragma unroll
                for (int n = 0; n < 4; ++n) {
                    s[n] = f32x4{0.f, 0.f, 0.f, 0.f};
                    s[n] = __builtin_amdgcn_mfma_f32_16x16x32_bf16(af[m][0], bk[n][0], s[n], 0, 0, 0);
                    s[n] = __builtin_amdgcn_mfma_f32_16x16x32_bf16(af[m][1], bk[n][1], s[n], 0, 0, 0);
                }
                __builtin_amdgcn_s_setprio(0);
                if (jt == it) {
#pragma unroll
                    for (int n = 0; n < 4; ++n)
#pragma unroll
                        for (int r = 0; r < 4; ++r) {
                            const int jj = j0 + n * 16 + lrow;
                            const int ii = i0 + m * 16 + 4 * kgrp + r;
                            if (jj < ii) rs[m][r] += __expf(0.125f * s[n][r]);
                        }
                } else {
#pragma unroll
                    for (int n = 0; n < 4; ++n)
#pragma unroll
                        for (int r = 0; r < 4; ++r)
                            rs[m][r] += __expf(0.125f * s[n][r]);
                }
            }
        }
#pragma unroll
        for (int off = 1; off < 16; off <<= 1)
#pragma unroll
            for (int m = 0; m < 4; ++m)
#pragma unroll
                for (int r = 0; r < 4; ++r)
                    rs[m][r] += __shfl_xor(rs[m][r], off);
        if (lrow == 0) {
#pragma unroll
            for (int m = 0; m < 4; ++m)
#pragma unroll
                for (int r = 0; r < 4; ++r)
                    rsp[wave][m * 16 + 4 * kgrp + r] = rs[m][r];
        }
        __syncthreads();
        if (tid < 64) {
            const float tot = rsp[0][tid] + rsp[1][tid] + rsp[2][tid] + rsp[3][tid];
            invl_g[(size_t)(b * HH + h) * TT + i0 + tid] =
                (tot > 0.f) ? 1.0f / (tot * (float)HH) : 0.f;
        }
        __syncthreads();
    }
}

// ---------------------------------------------------------------------------
// Pass 2: round-17/19 structure (25.6 KB LDS, K staged via global_load_lds,
// two-barrier phases, register prefetch of Q/ri one phase ahead,
// deterministic vmcnt(5) ledger).
// ---------------------------------------------------------------------------
__global__ __launch_bounds__(256) void dw_tile_kernel(
    const bf16_t* __restrict__ Qbf, const bf16_t* __restrict__ Kbf,
    const float* __restrict__ invl_g, bf16_t* __restrict__ dwbf,
    float* __restrict__ rsum_g)
{
    __shared__ alignas(16) bf16_t kbuf[2][64 * 64];   // 2 x 8 KB K tile
    __shared__ alignas(16) bf16_t stile[64][72];      // 9 KB out staging

    const int wave = threadIdx.x >> 6;   // = m (row quad)
    const int lane = threadIdx.x & 63;
    const int lrow = lane & 15;
    const int kgrp = lane >> 4;
    const int tid = threadIdx.x;
    const int b = blockIdx.y;

    // XCD swizzle: contiguous chunk of 66 tiles per XCD
    const int tidx = (blockIdx.x & 7) * 66 + (blockIdx.x >> 3);

    int it = (int)((sqrtf(8.0f * tidx + 1.0f) - 1.0f) * 0.5f);
    while ((it + 1) * (it + 2) / 2 <= tidx) ++it;
    while (it * (it + 1) / 2 > tidx) --it;
    const int jt = tidx - it * (it + 1) / 2;
    const bool diag = (it == jt);
    const int i0 = it * 64, j0 = jt * 64;
    const int m = wave;
    const int rbase = i0 + m * 16;            // my 16 rows
    const int nlim = diag ? (m + 1) : 4;

    // staging geometry: wave w covers rows 16w..16w+15 (2 KB = 2 issues)
    int prow[2], pchunk[2];
#pragma unroll
    for (int c = 0; c < 2; ++c) {
        const int p = wave * 2048 + c * 1024 + lane * 16;  // linear byte pos
        prow[c] = p >> 7;                                  // tile row
        pchunk[c] = ((p >> 4) & 7) ^ (prow[c] & 7);        // swizzled 16B chunk
    }
    const bf16_t* Kb0 = Kbf + ((size_t)b * HH * TT + j0) * DD;

    auto stage = [&](int h, int buf) {
#pragma unroll
        for (int c = 0; c < 2; ++c) {
            gll16(Kb0 + (size_t)h * TT * DD + prow[c] * DD + pchunk[c] * 8,
                  (bf16_t*)kbuf[buf] + wave * 1024 + c * 512);
        }
    };

    const bf16_t* qbase = Qbf + (size_t)(b * TT + rbase + lrow) * EE;
    const float*  ribase = invl_g + (size_t)b * HH * TT + rbase + 4 * kgrp;
    const int swz0 = (kgrp ^ (lrow & 7)) * 8;        // chunk 0-3 swizzled
    const int swz1 = ((4 + kgrp) ^ (lrow & 7)) * 8;  // chunk 4-7 swizzled

    f32x4 avg[4] = {};

    // prologue: Q0/ri0 register loads + stage0 (5 vmem ops outstanding)
    bf16x8 a0c = *(const bf16x8*)(qbase + kgrp * 8);
    bf16x8 a1c = *(const bf16x8*)(qbase + 32 + kgrp * 8);
    f32x4  ric = *(const f32x4*)(ribase);
    stage(0, 0);

#pragma unroll 1
    for (int h = 0; h < HH; ++h) {
        const int cur = h & 1;
        bf16x8 a0n, a1n;
        f32x4 rin;
        if (h + 1 < HH) {
            const bf16_t* qb = qbase + (h + 1) * DD;
            a0n = *(const bf16x8*)(qb + kgrp * 8);
            a1n = *(const bf16x8*)(qb + 32 + kgrp * 8);
            rin = *(const f32x4*)(ribase + (size_t)(h + 1) * TT);
            stage(h + 1, cur ^ 1);
            asm volatile("s_waitcnt vmcnt(5)" ::: "memory");
        } else {
            asm volatile("s_waitcnt vmcnt(0)" ::: "memory");
        }
        __builtin_amdgcn_s_barrier();      // kbuf[cur] fully visible

        const bf16_t* kb = kbuf[cur];
        f32x4 s[4];
        __builtin_amdgcn_s_setprio(1);
#pragma unroll
        for (int n = 0; n < 4; ++n) {
            if (n < nlim) {
                const int row = n * 16 + lrow;
                const bf16x8 b0 = *(const bf16x8*)(kb + row * 64 + swz0);
                const bf16x8 b1 = *(const bf16x8*)(kb + row * 64 + swz1);
                s[n] = f32x4{0.f, 0.f, 0.f, 0.f};
                s[n] = __builtin_amdgcn_mfma_f32_16x16x32_bf16(a0c, b0, s[n], 0, 0, 0);
                s[n] = __builtin_amdgcn_mfma_f32_16x16x32_bf16(a1c, b1, s[n], 0, 0, 0);
            }
        }
        __builtin_amdgcn_s_setprio(0);
#pragma unroll
        for (int n = 0; n < 4; ++n) {
            if (n < nlim) {
#pragma unroll
                for (int r = 0; r < 4; ++r)
                    avg[n][r] += __expf(0.125f * s[n][r]) * ric[r];
            }
        }
        __builtin_amdgcn_s_barrier();      // reads of kbuf[cur] done before overwrite
        if (h + 1 < HH) { a0c = a0n; a1c = a1n; ric = rin; }
    }

    // epilogue -> LDS (zeros for masked cells), per-cell gumbel + row sums
    float sr[4] = {0.f, 0.f, 0.f, 0.f};
#pragma unroll
    for (int n = 0; n < 4; ++n) {
        const int jj = j0 + n * 16 + lrow;
#pragma unroll
        for (int r = 0; r < 4; ++r) {
            const int rloc = m * 16 + 4 * kgrp + r;
            const int ii = i0 + rloc;
            float val = 0.f;
            if (n < nlim && jj < ii) {
                const float lg = fminf(fmaxf(avg[n][r], -40.0f), 40.0f);
                const float g = gumbel_for((unsigned)(b * TT + ii) * TT + (unsigned)jj);
                val = __expf((lg + g) * 0.5f);
            }
            sr[r] += val;
            stile[rloc][n * 16 + lrow] = (__bf16)val;
        }
    }
    // reduce tile-row sums across the 16 j-lanes, one atomicAdd per row
#pragma unroll
    for (int off = 1; off < 16; off <<= 1)
#pragma unroll
        for (int r = 0; r < 4; ++r) sr[r] += __shfl_xor(sr[r], off);
    if (lrow == 0) {
#pragma unroll
        for (int r = 0; r < 4; ++r)
            atomicAdd(&rsum_g[b * TT + rbase + 4 * kgrp + r], sr[r]);
    }
    __syncthreads();

    // coalesced copy-out: 8 lanes cover one 128B row segment
#pragma unroll
    for (int p = 0; p < 2; ++p) {
        const int idx = p * 256 + tid;
        const int row = idx >> 3, cg = idx & 7;
        *(bf16x8*)(dwbf + (size_t)(b * TT + i0 + row) * TT + j0 + cg * 8) =
            *(const bf16x8*)(&stile[row][cg * 8]);
    }
}

// ---------------------------------------------------------------------------
extern "C" void kernel_launch(void* const* d_in, const int* in_sizes, int n_in,
                              void* d_out, int out_size, void* d_ws, size_t ws_size,
                              hipStream_t stream) {
    const float* hs   = (const float*)d_in[0];   // (B,T,E) f32
    const float* W    = (const float*)d_in[1];   // (3E,E)  f32
    const float* bias = (const float*)d_in[2];   // (3E,)   f32
    float* out = (float*)d_out;                  // (B,T,E) f32

    char* ws = (char*)d_ws;
    bf16_t* dwbf   = (bf16_t*)ws;                                  // 16 MB (b,i,j)
    bf16_t* Qbf    = (bf16_t*)(ws + (size_t)16 * 1024 * 1024);     //  8 MB (b,t,e)
    bf16_t* Kbf    = (bf16_t*)(ws + (size_t)24 * 1024 * 1024);     //  8 MB (b,h,t,d)
    bf16_t* hsbf   = (bf16_t*)(ws + (size_t)32 * 1024 * 1024);     //  8 MB
    bf16_t* Wbf    = (bf16_t*)(ws + (size_t)40 * 1024 * 1024);     //  4 MB
    bf16_t* hsT    = (bf16_t*)(ws + (size_t)44 * 1024 * 1024);     //  8 MB (b,e,t)
    float*  invl_g = (float*) (ws + (size_t)52 * 1024 * 1024);     // 256 KB
    float*  rsum_g = (float*) (ws + (size_t)52 * 1024 * 1024 + 256 * 1024); // 16 KB

    prep_kernel<<<512, 256, 0, stream>>>(W, Wbf, dwbf, rsum_g);
    transpose_kernel<<<dim3(EE / 64, TT / 64, BB), 256, 0, stream>>>(hs, hsbf, hsT);
    qk_gemm_kernel<<<dim3(2048 / 128, 4096 / 128), 256, 0, stream>>>(hsbf, Wbf, bias, Qbf, Kbf);
    rowsum_kernel<<<dim3(16, HH, BB), 256, 0, stream>>>(Qbf, Kbf, invl_g);
    dw_tile_kernel<<<dim3(528, BB), 256, 0, stream>>>(Qbf, Kbf, invl_g, dwbf, rsum_g);
    out_gemm_kernel<<<dim3(EE / 128, TT / 128, BB), 256, 0, stream>>>(dwbf, hsT, rsum_g, out);
}